// Round 2
// baseline (189.852 us; speedup 1.0000x reference)
//
#include <hip/hip_runtime.h>
#include <cstdint>

#define FP8_MAX_F 448.0f

typedef float floatx4 __attribute__((ext_vector_type(4)));
typedef int   intx4   __attribute__((ext_vector_type(4)));
typedef int   intx8   __attribute__((ext_vector_type(8)));

static constexpr int Mdim = 2048;
static constexpr int Ndim = 4096;
static constexpr int Kdim = 4096;
static constexpr int BM = 128;
static constexpr int BN = 256;
static constexpr int BK = 128;   // fp8 bytes of K per staged tile
static constexpr int KT = Kdim / BK;  // 32 K-iterations

// amax: 8 float4 per thread, exact cover
static constexpr int A_XB = 1024;  // 2048*4096/4 / (256*8)
static constexpr int A_WB = 2048;  // 4096*4096/4 / (256*8)

__device__ __forceinline__ void async_load16(const void* g, void* l) {
  __builtin_amdgcn_global_load_lds((__attribute__((address_space(1))) void*)g,
                                   (__attribute__((address_space(3))) void*)l,
                                   16, 0, 0);
}

// ---------------------------------------------------------------------------
// Pass 1: per-block partial abs-max, both tensors in one dispatch.
// ---------------------------------------------------------------------------
__global__ void amax_partials(const float* __restrict__ x,
                              const float* __restrict__ w,
                              float* __restrict__ part) {
  const int b = blockIdx.x;
  const float4* p4;
  float* dst;
  int bid;
  if (b < A_XB) { p4 = (const float4*)x; dst = part;        bid = b; }
  else          { p4 = (const float4*)w; dst = part + A_XB; bid = b - A_XB; }
  const int tid = threadIdx.x;
  const int base = bid * 2048 + tid;
  float4 v[8];
#pragma unroll
  for (int u = 0; u < 8; u++) v[u] = p4[base + u * 256];
  float m = 0.f;
#pragma unroll
  for (int u = 0; u < 8; u++)
    m = fmaxf(m, fmaxf(fmaxf(fabsf(v[u].x), fabsf(v[u].y)),
                       fmaxf(fabsf(v[u].z), fabsf(v[u].w))));
#pragma unroll
  for (int off = 32; off > 0; off >>= 1)
    m = fmaxf(m, __shfl_down(m, off, 64));
  __shared__ float red[4];
  if ((tid & 63) == 0) red[tid >> 6] = m;
  __syncthreads();
  if (tid == 0)
    dst[bid] = fmaxf(fmaxf(red[0], red[1]), fmaxf(red[2], red[3]));
}

// ---------------------------------------------------------------------------
// Pass 2: reduce partials -> per-tensor amax, then quantize fp32 -> fp8
// e4m3fn (native OCP grid, RNE via v_cvt_pk_fp8_f32). Mirrors reference fp32
// arithmetic exactly: amax = max(|t|,1e-12); scale = 448/amax; clip; round.
// ---------------------------------------------------------------------------
__global__ void quant_both(const float* __restrict__ x,
                           const float* __restrict__ w,
                           const float* __restrict__ part,
                           unsigned int* __restrict__ qx,
                           unsigned int* __restrict__ qw,
                           float* __restrict__ scalars) {
  const int b = blockIdx.x;
  const float4* p4;
  const float* po;
  unsigned int* q;
  float* slot;
  int np, bid;
  if (b < A_XB) { p4 = (const float4*)x; po = part;        q = qx; np = A_XB; bid = b;        slot = scalars;     }
  else          { p4 = (const float4*)w; po = part + A_XB; q = qw; np = A_WB; bid = b - A_XB; slot = scalars + 1; }
  const int tid = threadIdx.x;

  float m = 0.f;
  for (int i = tid; i < np; i += 256) m = fmaxf(m, po[i]);
#pragma unroll
  for (int off = 32; off > 0; off >>= 1)
    m = fmaxf(m, __shfl_down(m, off, 64));
  __shared__ float red[4];
  __shared__ float amax_s;
  if ((tid & 63) == 0) red[tid >> 6] = m;
  __syncthreads();
  if (tid == 0) {
    float mm = fmaxf(fmaxf(fmaxf(red[0], red[1]), fmaxf(red[2], red[3])), 1e-12f);
    amax_s = mm;
    if (bid == 0) *slot = mm;
  }
  __syncthreads();
  const float scale = FP8_MAX_F / amax_s;

  const int base = bid * 2048 + tid;
#pragma unroll
  for (int u = 0; u < 8; u++) {
    float4 v = p4[base + u * 256];
    float a = fminf(fmaxf(v.x * scale, -FP8_MAX_F), FP8_MAX_F);
    float bb = fminf(fmaxf(v.y * scale, -FP8_MAX_F), FP8_MAX_F);
    float c = fminf(fmaxf(v.z * scale, -FP8_MAX_F), FP8_MAX_F);
    float d = fminf(fmaxf(v.w * scale, -FP8_MAX_F), FP8_MAX_F);
    unsigned int r = 0;
    r = __builtin_amdgcn_cvt_pk_fp8_f32(a, bb, r, false);
    r = __builtin_amdgcn_cvt_pk_fp8_f32(c, d, r, true);
    q[base + u * 256] = r;
  }
}

// ---------------------------------------------------------------------------
// FP8 GEMM (mfma_scale_f32_16x16x128_f8f6f4, unit e8m0 scales = plain fp8
// dot + fp32 acc). R6: T3+T4+T5 schedule. R4/R5 post-mortem: both the 64x32
// and 64x64 wave-tile versions hit the same ~3300 cyc/K-step wall at
// MfmaUtil ~28% — the invariant is the per-K-step __syncthreads, which
// compiles to s_waitcnt vmcnt(0) lgkmcnt(0) + s_barrier: an all-wave drain
// (the documented ~2-barrier-structure ceiling). This version removes the
// drain:
//   per K-step: [B1: all reads of dying buffer done] [issue 6 async loads
//   for kt+1 into other buffer] [s_waitcnt vmcnt(6) — only tile kt's 6
//   older loads must retire; kt+1's stay IN FLIGHT across the barrier]
//   [B2: tile kt resident for all waves] then 4 MFMA phases:
//   {ds_read fragment slice; lgkmcnt(0)+sched_barrier; setprio(1);
//    4 MFMA; setprio(0)} with NO intra-phase barriers — waves slip, so one
//   wave's ds_reads overlap another's MFMA burst, setprio arbitrates.
// Geometry unchanged: 128x256 block, 8 waves (2Mx4N), wave = 64x64
// (acc[4][4]), 96 KiB LDS, 1 block/CU, 256 blocks = exactly chip-filling.
//
// LDS rows of 128B = 8 chunks of 16B, XOR-swizzled: logical chunk c of row
// r at physical chunk c ^ (r&7); staging pins LDS dst to tid*16 and
// pre-swizzles the global source column. Fragment layouts (HW-verified
// m89/m148): A: lane holds A[m=lane&15][k=(lane>>4)*32+j], j=0..31;
// C/D: col=lane&15, row=(lane>>4)*4+reg.
// ---------------------------------------------------------------------------
__launch_bounds__(512, 2)
__global__ void gemm_fp8(const unsigned char* __restrict__ qx,
                         const unsigned char* __restrict__ qw,
                         const float* __restrict__ bias,
                         const float* __restrict__ scalars,
                         float* __restrict__ out) {
  __shared__ __align__(16) unsigned char As[2 * BM * BK];  // 2 x 16 KiB
  __shared__ __align__(16) unsigned char Bs[2 * BN * BK];  // 2 x 32 KiB

  const int tid = threadIdx.x;   // 0..511
  const int lane = tid & 63;
  const int wv = tid >> 6;       // 0..7
  const int wm = (wv & 1) * 64;  // wave M offset (2 rows of waves)
  const int wn = (wv >> 1) * 64; // wave N offset (4 cols of waves)

  // XCD-aware 2D swizzle: bid%8 = XCD; each XCD gets a 4(M) x 8(N) sub-grid.
  const int bid = blockIdx.x;            // 0..255
  const int xcd = bid & 7;
  const int idx = bid >> 3;              // 0..31
  const int by = (xcd >> 1) * 4 + (idx & 3);   // 0..15
  const int bx = (xcd & 1) * 8 + (idx >> 2);   // 0..15
  const int bm0 = by * BM;
  const int bn0 = bx * BN;

  // Staging source map: 6 async16 per thread per tile (A: 2 rounds of 64
  // rows, B: 4 rounds of 64 rows), LDS dst pinned to tid*16 per 8KB round.
  const int srow = tid >> 3;                          // 0..63
  const int sc = ((tid & 7) ^ ((tid >> 3) & 7)) << 4; // swizzled source col
  const unsigned char* gA0 = qx + (size_t)(bm0 + srow) * Kdim + sc;
  const unsigned char* gB0 = qw + (size_t)(bn0 + srow) * Kdim + sc;
  const size_t rstep = (size_t)64 * Kdim;
  const int lslot = tid * 16;

  floatx4 acc[4][4];
#pragma unroll
  for (int i = 0; i < 4; i++)
#pragma unroll
    for (int j = 0; j < 4; j++) acc[i][j] = (floatx4){0.f, 0.f, 0.f, 0.f};

  // Fragment read constants
  const int frow = lane & 15;
  const int h = lane >> 4;                   // k-block 0..3 (32B each)
  const int fr7 = frow & 7;
  const int kc0 = ((2 * h) ^ fr7) << 4;      // phys offset of logical chunk 2h
  const int kc1 = ((2 * h + 1) ^ fr7) << 4;  // phys offset of chunk 2h+1

#define LDFRAG(dst, basePtr, row16)                         \
  do {                                                      \
    const unsigned char* rp_ = (basePtr) + ((row16) + frow) * BK; \
    intx4 lo_ = *(const intx4*)(rp_ + kc0);                 \
    intx4 hi_ = *(const intx4*)(rp_ + kc1);                 \
    dst = __builtin_shufflevector(lo_, hi_, 0, 1, 2, 3, 4, 5, 6, 7); \
  } while (0)

  // Prologue: stage tile 0 into buffer 0 (6 loads/thread)
  async_load16(gA0, As + lslot);
  async_load16(gA0 + rstep, As + 8192 + lslot);
  async_load16(gB0, Bs + lslot);
  async_load16(gB0 + rstep, Bs + 8192 + lslot);
  async_load16(gB0 + 2 * rstep, Bs + 16384 + lslot);
  async_load16(gB0 + 3 * rstep, Bs + 24576 + lslot);

  for (int kt = 0; kt < KT; ++kt) {
    // B1: every wave has finished reading the buffer that the stage below
    // overwrites (its reads retired at its lgkmcnt(0) last iteration).
    __builtin_amdgcn_s_barrier();
    const int abuf = (kt & 1) * 16384;
    const int bbuf = (kt & 1) * 32768;
    if (kt + 1 < KT) {
      const int anb = ((kt + 1) & 1) * 16384;
      const int bnb = ((kt + 1) & 1) * 32768;
      const int k0 = (kt + 1) * BK;
      async_load16(gA0 + k0, As + anb + lslot);
      async_load16(gA0 + k0 + rstep, As + anb + 8192 + lslot);
      async_load16(gB0 + k0, Bs + bnb + lslot);
      async_load16(gB0 + k0 + rstep, Bs + bnb + 8192 + lslot);
      async_load16(gB0 + k0 + 2 * rstep, Bs + bnb + 16384 + lslot);
      async_load16(gB0 + k0 + 3 * rstep, Bs + bnb + 24576 + lslot);
      // counted wait: the 6 just-issued loads stay in flight; only tile
      // kt's 6 older loads must have retired.
      asm volatile("s_waitcnt vmcnt(6)" ::: "memory");
    } else {
      asm volatile("s_waitcnt vmcnt(0)" ::: "memory");
    }
    // B2: after this, ALL waves' tile-kt loads have landed in LDS.
    __builtin_amdgcn_s_barrier();
    __builtin_amdgcn_sched_barrier(0);

    const unsigned char* Ab = As + abuf;
    const unsigned char* Bb = Bs + bbuf;

    // Phase 0: all B fragments + A row 0 -> acc[0][*]
    intx8 bf[4], a;
    LDFRAG(bf[0], Bb, wn + 0);
    LDFRAG(bf[1], Bb, wn + 16);
    LDFRAG(bf[2], Bb, wn + 32);
    LDFRAG(bf[3], Bb, wn + 48);
    LDFRAG(a, Ab, wm + 0);
    asm volatile("s_waitcnt lgkmcnt(0)" ::: "memory");
    __builtin_amdgcn_sched_barrier(0);
    __builtin_amdgcn_s_setprio(1);
#pragma unroll
    for (int j = 0; j < 4; j++)
      acc[0][j] = __builtin_amdgcn_mfma_scale_f32_16x16x128_f8f6f4(
          a, bf[j], acc[0][j], 0, 0, 0, 0x7F7F7F7F, 0, 0x7F7F7F7F);
    __builtin_amdgcn_s_setprio(0);

    // Phases 1..3: A row p -> acc[p][*]  (ds_read issue may float up into
    // the previous MFMA burst; lgkm wait + sched_barrier pin the burst)
#pragma unroll
    for (int p = 1; p < 4; p++) {
      LDFRAG(a, Ab, wm + p * 16);
      asm volatile("s_waitcnt lgkmcnt(0)" ::: "memory");
      __builtin_amdgcn_sched_barrier(0);
      __builtin_amdgcn_s_setprio(1);
#pragma unroll
      for (int j = 0; j < 4; j++)
        acc[p][j] = __builtin_amdgcn_mfma_scale_f32_16x16x128_f8f6f4(
            a, bf[j], acc[p][j], 0, 0, 0, 0x7F7F7F7F, 0, 0x7F7F7F7F);
      __builtin_amdgcn_s_setprio(0);
    }
  }

  // Dequant scale, mirroring reference fp32 arithmetic exactly.
  float ax = fmaxf(scalars[0], 1e-12f);
  float aw = fmaxf(scalars[1], 1e-12f);
  float cs = (1.0f / (FP8_MAX_F / ax)) * (1.0f / (FP8_MAX_F / aw));

  const int crow = bm0 + wm + (lane >> 4) * 4;
  const int ccol = bn0 + wn + (lane & 15);
#pragma unroll
  for (int j = 0; j < 4; j++) {
    float bv = bias[ccol + j * 16];
#pragma unroll
    for (int i = 0; i < 4; i++) {
#pragma unroll
      for (int r = 0; r < 4; r++) {
        out[(size_t)(crow + i * 16 + r) * Ndim + (ccol + j * 16)] =
            acc[i][j][r] * cs + bv;
      }
    }
  }
#undef LDFRAG
}

extern "C" void kernel_launch(void* const* d_in, const int* in_sizes, int n_in,
                              void* d_out, int out_size, void* d_ws, size_t ws_size,
                              hipStream_t stream) {
  const float* x = (const float*)d_in[0];     // [M,K] fp32
  const float* w = (const float*)d_in[1];     // [N,K] fp32
  const float* bias = (const float*)d_in[2];  // [N] fp32
  float* out = (float*)d_out;                 // [M,N] fp32

  // Workspace: partials (3072 f) | scalars (2 f) | pad to 32 KiB | qx | qw
  float* part = (float*)d_ws;
  float* scalars = part + 4096;
  unsigned char* qx = (unsigned char*)d_ws + 32768;
  unsigned char* qw = qx + (size_t)Mdim * Kdim;

  amax_partials<<<A_XB + A_WB, 256, 0, stream>>>(x, w, part);
  quant_both<<<A_XB + A_WB, 256, 0, stream>>>(x, w, part,
                                              (unsigned int*)qx, (unsigned int*)qw,
                                              scalars);
  gemm_fp8<<<256, 512, 0, stream>>>(qx, qw, bias, scalars, out);
}

// Round 3
// 181.251 us; speedup vs baseline: 1.0475x; 1.0475x over previous
//
#include <hip/hip_runtime.h>
#include <cstdint>

#define FP8_MAX_F 448.0f

typedef float floatx4 __attribute__((ext_vector_type(4)));
typedef int   intx4   __attribute__((ext_vector_type(4)));
typedef int   intx8   __attribute__((ext_vector_type(8)));

static constexpr int Mdim = 2048;
static constexpr int Ndim = 4096;
static constexpr int Kdim = 4096;
static constexpr int BM = 128;
static constexpr int BN = 128;
static constexpr int BK = 128;   // fp8 bytes of K per staged tile
static constexpr int KT = Kdim / BK;  // 32 K-iterations

// amax: 8 float4 per thread, exact cover
static constexpr int A_XB = 1024;  // 2048*4096/4 / (256*8)
static constexpr int A_WB = 2048;  // 4096*4096/4 / (256*8)

__device__ __forceinline__ void async_load16(const void* g, void* l) {
  __builtin_amdgcn_global_load_lds((__attribute__((address_space(1))) void*)g,
                                   (__attribute__((address_space(3))) void*)l,
                                   16, 0, 0);
}

// ---------------------------------------------------------------------------
// Pass 1: per-block partial abs-max, both tensors in one dispatch.
// ---------------------------------------------------------------------------
__global__ void amax_partials(const float* __restrict__ x,
                              const float* __restrict__ w,
                              float* __restrict__ part) {
  const int b = blockIdx.x;
  const float4* p4;
  float* dst;
  int bid;
  if (b < A_XB) { p4 = (const float4*)x; dst = part;        bid = b; }
  else          { p4 = (const float4*)w; dst = part + A_XB; bid = b - A_XB; }
  const int tid = threadIdx.x;
  const int base = bid * 2048 + tid;
  float4 v[8];
#pragma unroll
  for (int u = 0; u < 8; u++) v[u] = p4[base + u * 256];
  float m = 0.f;
#pragma unroll
  for (int u = 0; u < 8; u++)
    m = fmaxf(m, fmaxf(fmaxf(fabsf(v[u].x), fabsf(v[u].y)),
                       fmaxf(fabsf(v[u].z), fabsf(v[u].w))));
#pragma unroll
  for (int off = 32; off > 0; off >>= 1)
    m = fmaxf(m, __shfl_down(m, off, 64));
  __shared__ float red[4];
  if ((tid & 63) == 0) red[tid >> 6] = m;
  __syncthreads();
  if (tid == 0)
    dst[bid] = fmaxf(fmaxf(red[0], red[1]), fmaxf(red[2], red[3]));
}

// ---------------------------------------------------------------------------
// Pass 2: reduce partials -> per-tensor amax, then quantize fp32 -> fp8
// e4m3fn (native OCP grid, RNE via v_cvt_pk_fp8_f32). Mirrors reference fp32
// arithmetic exactly: amax = max(|t|,1e-12); scale = 448/amax; clip; round.
// ---------------------------------------------------------------------------
__global__ void quant_both(const float* __restrict__ x,
                           const float* __restrict__ w,
                           const float* __restrict__ part,
                           unsigned int* __restrict__ qx,
                           unsigned int* __restrict__ qw,
                           float* __restrict__ scalars) {
  const int b = blockIdx.x;
  const float4* p4;
  const float* po;
  unsigned int* q;
  float* slot;
  int np, bid;
  if (b < A_XB) { p4 = (const float4*)x; po = part;        q = qx; np = A_XB; bid = b;        slot = scalars;     }
  else          { p4 = (const float4*)w; po = part + A_XB; q = qw; np = A_WB; bid = b - A_XB; slot = scalars + 1; }
  const int tid = threadIdx.x;

  float m = 0.f;
  for (int i = tid; i < np; i += 256) m = fmaxf(m, po[i]);
#pragma unroll
  for (int off = 32; off > 0; off >>= 1)
    m = fmaxf(m, __shfl_down(m, off, 64));
  __shared__ float red[4];
  __shared__ float amax_s;
  if ((tid & 63) == 0) red[tid >> 6] = m;
  __syncthreads();
  if (tid == 0) {
    float mm = fmaxf(fmaxf(fmaxf(red[0], red[1]), fmaxf(red[2], red[3])), 1e-12f);
    amax_s = mm;
    if (bid == 0) *slot = mm;
  }
  __syncthreads();
  const float scale = FP8_MAX_F / amax_s;

  const int base = bid * 2048 + tid;
#pragma unroll
  for (int u = 0; u < 8; u++) {
    float4 v = p4[base + u * 256];
    float a = fminf(fmaxf(v.x * scale, -FP8_MAX_F), FP8_MAX_F);
    float bb = fminf(fmaxf(v.y * scale, -FP8_MAX_F), FP8_MAX_F);
    float c = fminf(fmaxf(v.z * scale, -FP8_MAX_F), FP8_MAX_F);
    float d = fminf(fmaxf(v.w * scale, -FP8_MAX_F), FP8_MAX_F);
    unsigned int r = 0;
    r = __builtin_amdgcn_cvt_pk_fp8_f32(a, bb, r, false);
    r = __builtin_amdgcn_cvt_pk_fp8_f32(c, d, r, true);
    q[base + u * 256] = r;
  }
}

// ---------------------------------------------------------------------------
// FP8 GEMM (mfma_scale_f32_16x16x128_f8f6f4, unit e8m0 scales = plain fp8
// dot + fp32 acc). R7: combine the two independently-proven wins.
// R4..R6 post-mortem: R4 (64x32 wave, 2 blocks/CU) = 43.4us; R5 (64x64
// wave = -33% LDS reads, but 1 block/CU) = 44.8; R6 (R5 + pinned schedule)
// = 54.7. The LDS-read cut bought nothing at 1 block/CU because the
// per-K-step vmcnt(0)+barrier drain was no longer hidden; R4 hid it behind
// the co-resident second block (cross-block overlap, m114 mechanism).
// R6's sched_barrier/lgkm pinning was the m141 regression. So:
//   - wave tile 64x64 (acc[4][4], 1024 B LDS-read per MFMA, vs R4's 1536)
//   - BM=BN=128, 256 threads = 4 waves (2Mx4... 2Mx2N), 64 KiB LDS
//     -> 2 blocks/CU (128 KiB), 8 waves/CU = 2/SIMD: drain hiding restored
//   - loop structure byte-identical to R4's proven single-__syncthreads
//     double-buffered pipeline; NO asm waits, NO sched_barriers.
// Grid 32x16 = 512 blocks (2/CU exactly), bijective XCD swizzle (512%8==0):
// each XCD owns a 4(by) x 16(bx) sub-grid -> per-K-step XCD working set
// ~320 KB in its L2, A-panels reused 16x, B-panels 4x.
//
// LDS rows of 128B = 8 chunks of 16B, XOR-swizzled: logical chunk c of row
// r at physical chunk c ^ (r&7); staging pins LDS dst to tid*16 per 4KB
// round (32 rows) and pre-swizzles the global source column (row&7 is
// round-invariant since rounds step 32 rows). Fragment layouts (HW-verified
// m89/m148): A: lane holds A[m=lane&15][k=(lane>>4)*32+j], j=0..31;
// C/D: col=lane&15, row=(lane>>4)*4+reg.
// ---------------------------------------------------------------------------
__launch_bounds__(256, 2)
__global__ void gemm_fp8(const unsigned char* __restrict__ qx,
                         const unsigned char* __restrict__ qw,
                         const float* __restrict__ bias,
                         const float* __restrict__ scalars,
                         float* __restrict__ out) {
  __shared__ __align__(16) unsigned char As[2 * BM * BK];  // 2 x 16 KiB
  __shared__ __align__(16) unsigned char Bs[2 * BN * BK];  // 2 x 16 KiB

  const int tid = threadIdx.x;   // 0..255
  const int lane = tid & 63;
  const int wv = tid >> 6;       // 0..3
  const int wm = (wv & 1) * 64;  // wave M offset (2 rows of waves)
  const int wn = (wv >> 1) * 64; // wave N offset (2 cols of waves)

  // XCD-aware bijective swizzle over the 16(by) x 32(bx) block grid:
  // xcd = bid&7; each XCD owns by in [(xcd&3)*4, +4), bx in [(xcd>>2)*16, +16).
  const int bid = blockIdx.x;            // 0..511
  const int xcd = bid & 7;
  const int idx = bid >> 3;              // 0..63
  const int by = (xcd & 3) * 4 + (idx & 3);     // 0..15
  const int bx = (xcd >> 2) * 16 + (idx >> 2);  // 0..31
  const int bm0 = by * BM;
  const int bn0 = bx * BN;

  // Staging source map: 8 async16 per thread per tile (A: 4 rounds of 32
  // rows, B: 4 rounds of 32 rows), LDS dst pinned to tid*16 per 4KB round.
  const int srow = tid >> 3;                          // 0..31
  const int sc = ((tid & 7) ^ ((tid >> 3) & 7)) << 4; // swizzled source col
  const unsigned char* gA0 = qx + (size_t)(bm0 + srow) * Kdim + sc;
  const unsigned char* gB0 = qw + (size_t)(bn0 + srow) * Kdim + sc;
  const size_t rstep = (size_t)32 * Kdim;
  const int lslot = tid * 16;

  floatx4 acc[4][4];
#pragma unroll
  for (int i = 0; i < 4; i++)
#pragma unroll
    for (int j = 0; j < 4; j++) acc[i][j] = (floatx4){0.f, 0.f, 0.f, 0.f};

  // Fragment read constants
  const int frow = lane & 15;
  const int h = lane >> 4;                   // k-block 0..3 (32B each)
  const int fr7 = frow & 7;
  const int kc0 = ((2 * h) ^ fr7) << 4;      // phys offset of logical chunk 2h
  const int kc1 = ((2 * h + 1) ^ fr7) << 4;  // phys offset of chunk 2h+1

  // Prologue: stage tile 0 into buffer 0 (8 loads/thread)
#pragma unroll
  for (int r = 0; r < 4; r++) {
    async_load16(gA0 + r * rstep, As + r * 4096 + lslot);
    async_load16(gB0 + r * rstep, Bs + r * 4096 + lslot);
  }

  for (int kt = 0; kt < KT; ++kt) {
    __syncthreads();  // drains loads issued LAST iter (a full compute ago);
                      // co-resident block hides the drain on this CU.
    const int buf = (kt & 1) * 16384;
    if (kt + 1 < KT) {
      const int nbuf = ((kt + 1) & 1) * 16384;
      const int k0 = (kt + 1) * BK;
#pragma unroll
      for (int r = 0; r < 4; r++) {
        async_load16(gA0 + k0 + r * rstep, As + nbuf + r * 4096 + lslot);
        async_load16(gB0 + k0 + r * rstep, Bs + nbuf + r * 4096 + lslot);
      }
    }

    intx8 af[4], bf[4];
#pragma unroll
    for (int t = 0; t < 4; t++) {
      const unsigned char* ra = As + buf + (wm + t * 16 + frow) * BK;
      intx4 lo = *(const intx4*)(ra + kc0);
      intx4 hi = *(const intx4*)(ra + kc1);
      af[t] = __builtin_shufflevector(lo, hi, 0, 1, 2, 3, 4, 5, 6, 7);
    }
#pragma unroll
    for (int u = 0; u < 4; u++) {
      const unsigned char* rb = Bs + buf + (wn + u * 16 + frow) * BK;
      intx4 lo = *(const intx4*)(rb + kc0);
      intx4 hi = *(const intx4*)(rb + kc1);
      bf[u] = __builtin_shufflevector(lo, hi, 0, 1, 2, 3, 4, 5, 6, 7);
    }
#pragma unroll
    for (int i = 0; i < 4; i++)
#pragma unroll
      for (int j = 0; j < 4; j++)
        acc[i][j] = __builtin_amdgcn_mfma_scale_f32_16x16x128_f8f6f4(
            af[i], bf[j], acc[i][j], 0 /*A=fp8*/, 0 /*B=fp8*/,
            0, 0x7F7F7F7F, 0, 0x7F7F7F7F);  // unit scales (e8m0 127 = 2^0)
  }

  // Dequant scale, mirroring reference fp32 arithmetic exactly.
  float ax = fmaxf(scalars[0], 1e-12f);
  float aw = fmaxf(scalars[1], 1e-12f);
  float cs = (1.0f / (FP8_MAX_F / ax)) * (1.0f / (FP8_MAX_F / aw));

  const int crow = bm0 + wm + (lane >> 4) * 4;
  const int ccol = bn0 + wn + (lane & 15);
#pragma unroll
  for (int j = 0; j < 4; j++) {
    float bv = bias[ccol + j * 16];
#pragma unroll
    for (int i = 0; i < 4; i++) {
#pragma unroll
      for (int r = 0; r < 4; r++) {
        out[(size_t)(crow + i * 16 + r) * Ndim + (ccol + j * 16)] =
            acc[i][j][r] * cs + bv;
      }
    }
  }
}

extern "C" void kernel_launch(void* const* d_in, const int* in_sizes, int n_in,
                              void* d_out, int out_size, void* d_ws, size_t ws_size,
                              hipStream_t stream) {
  const float* x = (const float*)d_in[0];     // [M,K] fp32
  const float* w = (const float*)d_in[1];     // [N,K] fp32
  const float* bias = (const float*)d_in[2];  // [N] fp32
  float* out = (float*)d_out;                 // [M,N] fp32

  // Workspace: partials (3072 f) | scalars (2 f) | pad to 32 KiB | qx | qw
  float* part = (float*)d_ws;
  float* scalars = part + 4096;
  unsigned char* qx = (unsigned char*)d_ws + 32768;
  unsigned char* qw = qx + (size_t)Mdim * Kdim;

  amax_partials<<<A_XB + A_WB, 256, 0, stream>>>(x, w, part);
  quant_both<<<A_XB + A_WB, 256, 0, stream>>>(x, w, part,
                                              (unsigned int*)qx, (unsigned int*)qw,
                                              scalars);
  gemm_fp8<<<512, 256, 0, stream>>>(qx, qw, bias, scalars, out);
}